// Round 12
// baseline (290.070 us; speedup 1.0000x reference)
//
#include <hip/hip_runtime.h>
#include <hip/hip_bf16.h>
#include <cmath>

#define RPB      32        // rows per fine bucket
#define FB_CAP   1280      // fine-bucket slot capacity (mean 1024, +8 sigma)
#define SB_SHIFT 11        // 2048 rows per super-bucket
#define NSB_MAX  64
#define TILE     2048      // edges per binning tile
#define CH_PER_SB 34       // pass-2 chunks per super-bucket (cap/34 <= TILE)
#define CPAD     32        // cursor1 padding: 1 counter per 128B line

typedef __attribute__((ext_vector_type(8))) short short8;
typedef __attribute__((ext_vector_type(4))) float floatx4;

__device__ __forceinline__ unsigned short f2bf(float f) {
    unsigned int u = __float_as_uint(f);
    u += 0x7FFFu + ((u >> 16) & 1u);   // RNE
    return (unsigned short)(u >> 16);
}

// ---------------- gemm body: A from x (reg), B staged in LDS -----------------
// (R11 version, verified.) Epilogue buffer reuses Wb: total LDS 34.8 KB.
__device__ __forceinline__ void gemm_body(
    char* smraw, const float* __restrict__ x,
    const unsigned short* __restrict__ Wbg, const float* __restrict__ b,
    unsigned short* __restrict__ Yb, int N, int blk)
{
    unsigned short* Wb = (unsigned short*)smraw;      // [128][136] = 34816 B
    const int t    = threadIdx.x;
    const int wave = t >> 6;
    const int lane = t & 63;
    const int col  = lane & 15;
    const int quad = lane >> 4;
    const int rowbase = blk * 64;
    const int mrow = wave * 16;

#pragma unroll
    for (int i = 0; i < 8; ++i) {          // W: 2048 chunks of 8 bf16 (16B)
        const int idx = t + 256 * i;
        const int o = idx >> 4, k8 = (idx & 15) * 8;
        *(uint4*)&Wb[o * 136 + k8] = *(const uint4*)&Wbg[idx * 8];
    }

    short8 af[4];
    const int arow = rowbase + mrow + col;
    if (arow < N) {
#pragma unroll
        for (int kk = 0; kk < 4; ++kk) {
            const float4 v0 = *(const float4*)&x[(size_t)arow * 128 + kk * 32 + quad * 8];
            const float4 v1 = *(const float4*)&x[(size_t)arow * 128 + kk * 32 + quad * 8 + 4];
            short8 a;
            a[0] = (short)f2bf(v0.x); a[1] = (short)f2bf(v0.y);
            a[2] = (short)f2bf(v0.z); a[3] = (short)f2bf(v0.w);
            a[4] = (short)f2bf(v1.x); a[5] = (short)f2bf(v1.y);
            a[6] = (short)f2bf(v1.z); a[7] = (short)f2bf(v1.w);
            af[kk] = a;
        }
    } else {
#pragma unroll
        for (int kk = 0; kk < 4; ++kk) {
            short8 a;
#pragma unroll
            for (int j = 0; j < 8; ++j) a[j] = 0;
            af[kk] = a;
        }
    }

    float bias[8];
#pragma unroll
    for (int nt = 0; nt < 8; ++nt) bias[nt] = b[nt * 16 + col];

    __syncthreads();                       // Wb staged

    floatx4 acc[8] = {};
#pragma unroll
    for (int kk = 0; kk < 4; ++kk) {
#pragma unroll
        for (int nt = 0; nt < 8; ++nt) {
            const short8 bf = *(const short8*)&Wb[(nt * 16 + col) * 136 + kk * 32 + quad * 8];
            acc[nt] = __builtin_amdgcn_mfma_f32_16x16x32_bf16(af[kk], bf, acc[nt], 0, 0, 0);
        }
    }
    __syncthreads();                       // all Wb reads done; reuse as Eb

    unsigned short* Eb = Wb;               // [64][136]
#pragma unroll
    for (int nt = 0; nt < 8; ++nt) {
#pragma unroll
        for (int reg = 0; reg < 4; ++reg)
            Eb[(mrow + quad * 4 + reg) * 136 + nt * 16 + col] =
                f2bf(acc[nt][reg] + bias[nt]);
    }
    __syncthreads();
#pragma unroll
    for (int i = 0; i < 4; ++i) {          // 1024 chunks of 16B: 64 rows x 16
        const int idx = t + 256 * i;
        const int row = idx >> 4, c16 = (idx & 15) * 8;
        const int gr  = rowbase + row;
        if (gr < N)
            *(uint4*)&Yb[(size_t)gr * 128 + c16] = *(const uint4*)&Eb[row * 136 + c16];
    }
}

// ---------------- pass1 body: register-held edges, direct sorted scatter -----
// Edges live in registers across hist->scan; scatter writes DATA to its sorted
// LDS slot (+1B bin tag); final pass streams sequentially to global. Deletes
// the perm indirection and staging sbuf/sbin writes (~9-10 -> ~6 LDS ops/edge).
// LDS 19 KB.
__device__ __forceinline__ void pass1_body(
    char* smraw, const int* __restrict__ rows, const int* __restrict__ cols,
    const float* __restrict__ vals, int* __restrict__ cursor1,
    int2* __restrict__ pairs1, int E, int blk)
{
    int2* sbuf            = (int2*)smraw;                      // [TILE] 16KB (sorted)
    unsigned char* sbin2  = (unsigned char*)(sbuf + TILE);     // [TILE] 2KB (bin@pos)
    int* hist  = (int*)(sbin2 + TILE);                         // [64]
    int* off   = hist + NSB_MAX;
    int* gbase = off + NSB_MAX;
    int* cur   = gbase + NSB_MAX;
    const int t  = threadIdx.x;
    const int lane = t & 63;
    const int lo = blk * TILE;
    const int cnt = min(TILE, E - lo);

    if (t < NSB_MAX) hist[t] = 0;
    __syncthreads();

    int2 pr[8];
    int  bn[8];
#pragma unroll
    for (int j = 0; j < 8; ++j) {          // TILE/256 == 8
        const int i = t + 256 * j;
        bn[j] = -1;
        if (i < cnt) {
            const int   r = rows[lo + i];
            const int   c = cols[lo + i];
            const float v = vals[lo + i];
            pr[j] = make_int2(((r & 2047) << 17) | c, __float_as_int(v));
            bn[j] = r >> SB_SHIFT;
            atomicAdd(&hist[bn[j]], 1);
        }
    }
    __syncthreads();
    if (t < NSB_MAX) {                     // wave-0 parallel exclusive scan
        const int h = hist[t];
        int s = h;
#pragma unroll
        for (int d = 1; d < NSB_MAX; d <<= 1) {
            const int n = __shfl_up(s, d);
            if (lane >= d) s += n;
        }
        off[t] = s - h;
        cur[t] = s - h;
        if (h > 0) gbase[t] = atomicAdd(&cursor1[t * CPAD], h);
    }
    __syncthreads();
#pragma unroll
    for (int j = 0; j < 8; ++j) {          // scatter data to sorted slot
        if (bn[j] >= 0) {
            const int pos = atomicAdd(&cur[bn[j]], 1);
            sbuf[pos]  = pr[j];
            sbin2[pos] = (unsigned char)bn[j];
        }
    }
    __syncthreads();
    for (int i = t; i < cnt; i += 256) {   // sequential stream to global runs
        const int bb = sbin2[i];
        pairs1[gbase[bb] + (i - off[bb])] = sbuf[i];
    }
}

// ---------------- K1: gemm ∥ pass1 (interleaved block types) -----------------
__global__ __launch_bounds__(256) void fused_gemm_pass1_kernel(
    const float* __restrict__ x, const unsigned short* __restrict__ Wbg,
    const float* __restrict__ b, unsigned short* __restrict__ Yb, int N, int GB,
    const int* __restrict__ rows, const int* __restrict__ cols,
    const float* __restrict__ vals, int* __restrict__ cursor1,
    int2* __restrict__ pairs1, int E, int PB)
{
    extern __shared__ __align__(16) char smraw[];
    const int bid = blockIdx.x;
    const int mn  = min(GB, PB);
    int type, sub;
    if (bid < 2 * mn) { type = bid & 1; sub = bid >> 1; }
    else              { type = (GB > PB) ? 0 : 1; sub = mn + (bid - 2 * mn); }
    if (type == 0) gemm_body(smraw, x, Wbg, b, Yb, N, sub);
    else           pass1_body(smraw, rows, cols, vals, cursor1, pairs1, E, sub);
}

// ---------------- standalone GEMM (fallback-serialized path) -----------------
__global__ __launch_bounds__(256) void gemm_mfma_kernel(
    const float* __restrict__ x, const unsigned short* __restrict__ Wbg,
    const float* __restrict__ b, unsigned short* __restrict__ Yb, int N)
{
    __shared__ __align__(16) char sm[128 * 136 * 2];
    gemm_body(sm, x, Wbg, b, Yb, N, blockIdx.x);
}

// ---------------- standalone pass1 (fallback-serialized path) ----------------
__global__ __launch_bounds__(256) void pass1_kernel(
    const int* __restrict__ rows, const int* __restrict__ cols,
    const float* __restrict__ vals, int* __restrict__ cursor1,
    int2* __restrict__ pairs1, int E)
{
    __shared__ __align__(16) char sm[TILE * 8 + TILE + NSB_MAX * 16];
    pass1_body(sm, rows, cols, vals, cursor1, pairs1, E, blockIdx.x);
}

// ---------------- P0: init cursors + convert W to bf16 -----------------------
__global__ __launch_bounds__(256) void init_cursor_kernel(
    int* __restrict__ cursor1, int* __restrict__ cursor2, int SB_CAP, int NB,
    const float* __restrict__ W, unsigned short* __restrict__ Wbg)
{
    const int i = blockIdx.x * blockDim.x + threadIdx.x;
    if (i < NSB_MAX) cursor1[i * CPAD] = i * SB_CAP;
    if (i < NB)      cursor2[i] = i * FB_CAP;
    const int stride = gridDim.x * blockDim.x;
    for (int j = i; j < 128 * 128 / 4; j += stride) {
        const float4 v = ((const float4*)W)[j];
        uint2 u;
        u.x = (unsigned)f2bf(v.x) | ((unsigned)f2bf(v.y) << 16);
        u.y = (unsigned)f2bf(v.z) | ((unsigned)f2bf(v.w) << 16);
        ((uint2*)Wbg)[j] = u;
    }
}

// ---------------- P2: register-held chunk sort by fine bucket ----------------
__global__ __launch_bounds__(256) void pass2_kernel(
    const int* __restrict__ cursor1, int* __restrict__ cursor2,
    const int2* __restrict__ pairs1, int2* __restrict__ pairs2, int SB_CAP)
{
    __shared__ __align__(16) int2 sbuf[TILE];
    __shared__ unsigned char sbin2[TILE];
    __shared__ int hist[64], off[64], gbase[64], cur[64];
    const int t   = threadIdx.x;
    const int lane = t & 63;
    const int sb  = blockIdx.x / CH_PER_SB;
    const int ch  = blockIdx.x % CH_PER_SB;
    const int base = sb * SB_CAP;
    const int scnt = cursor1[sb * CPAD] - base;
    const int csz  = (scnt + CH_PER_SB - 1) / CH_PER_SB;
    const int lo   = ch * csz;
    const int cnt  = max(0, min(csz, scnt - lo));

    if (t < 64) hist[t] = 0;
    __syncthreads();

    int2 pr[8];
    int  bn[8];
#pragma unroll
    for (int j = 0; j < 8; ++j) {          // csz <= TILE == 8*256
        const int i = t + 256 * j;
        bn[j] = -1;
        if (i < cnt) {
            const int2 p = pairs1[base + lo + i];
            pr[j] = p;
            bn[j] = (int)((unsigned)p.x >> 22);
            atomicAdd(&hist[bn[j]], 1);
        }
    }
    __syncthreads();
    if (t < 64) {                          // wave-0 parallel exclusive scan
        const int h = hist[t];
        int s = h;
#pragma unroll
        for (int d = 1; d < 64; d <<= 1) {
            const int n = __shfl_up(s, d);
            if (lane >= d) s += n;
        }
        off[t] = s - h;
        cur[t] = s - h;
        if (h > 0) gbase[t] = atomicAdd(&cursor2[sb * 64 + t], h);
    }
    __syncthreads();
#pragma unroll
    for (int j = 0; j < 8; ++j) {          // scatter data to sorted slot
        if (bn[j] >= 0) {
            const int pos = atomicAdd(&cur[bn[j]], 1);
            sbuf[pos]  = make_int2(pr[j].x & 0x3FFFFF, pr[j].y);  // keep ((row&31)<<17)|col
            sbin2[pos] = (unsigned char)bn[j];
        }
    }
    __syncthreads();
    for (int i = t; i < cnt; i += 256) {   // sequential stream to global runs
        const int bb = sbin2[i];
        pairs2[gbase[bb] + (i - off[bb])] = sbuf[i];
    }
}

// ---------------- P3: counting-sort + 4-edge-wide gather + ELU ---------------
// FROZEN at ~115us total. b0 offset allows a 2-dispatch split purely for
// rocprof visibility (top-5 then exposes the fused/pass2 tier).
__global__ __launch_bounds__(256) void sortgather_kernel(
    const int* __restrict__ cursor2, const int2* __restrict__ pairs2,
    const unsigned int* __restrict__ Yu, float* __restrict__ out, int N, int b0)
{
    __shared__ __align__(16) int2 dbuf[FB_CAP + 4];
    __shared__ int hist[RPB];
    __shared__ int off[RPB];
    __shared__ int cur[RPB];
    __shared__ int rowtick;
    const int b    = blockIdx.x + b0;
    const int t    = threadIdx.x;
    const int lane = t & 63;
    const int slot = b * FB_CAP;
    int cnt = cursor2[b] - slot;
    if (cnt > FB_CAP) cnt = FB_CAP;

    if (t < RPB) hist[t] = 0;
    if (t == 0) rowtick = 0;
    __syncthreads();
    for (int i = t; i < cnt; i += 256) {       // pass A: histogram (global read)
        atomicAdd(&hist[pairs2[slot + i].x >> 17], 1);
    }
    __syncthreads();
    if (t == 0) {
        int run = 0;
#pragma unroll
        for (int k = 0; k < RPB; ++k) { off[k] = run; cur[k] = run; run += hist[k]; }
    }
    __syncthreads();
    for (int i = t; i < cnt; i += 256) {       // pass B: scatter (global re-read)
        const int2 p   = pairs2[slot + i];
        const int  pos = atomicAdd(&cur[p.x >> 17], 1);
        dbuf[pos] = make_int2(p.x & 0x1FFFF, p.y);
    }
    if (t < 4) dbuf[cnt + t] = make_int2(0, 0);   // pad: tail over-reads hit row 0, v=0
    __syncthreads();

    const int sub   = lane >> 4;   // which of the 4 edges in a chunk
    const int qlane = lane & 15;   // 16 lanes span one 256B Y row (dwordx4 each)

    for (;;) {
        int rl = 0;
        if (lane == 0) rl = atomicAdd(&rowtick, 1);
        rl = __shfl(rl, 0);
        if (rl >= RPB) break;
        const int gr = b * RPB + rl;
        if (gr >= N) continue;
        const int s = off[rl];
        const int e = s + hist[rl];

        float acc0 = 0.f, acc1 = 0.f, acc2 = 0.f, acc3 = 0.f;
        float acc4 = 0.f, acc5 = 0.f, acc6 = 0.f, acc7 = 0.f;
#pragma unroll 2
        for (int j = s; j < e; j += 4) {
            const int2 p = dbuf[j + sub];            // 4 distinct broadcast addrs
            float v = __int_as_float(p.y);
            v = (j + sub < e) ? v : 0.0f;            // mask tail (y stays valid)
            const uint4 y = *(const uint4*)&Yu[((unsigned)p.x << 6) + qlane * 4];
            acc0 = fmaf(v, __uint_as_float(y.x << 16), acc0);
            acc1 = fmaf(v, __uint_as_float(y.x & 0xFFFF0000u), acc1);
            acc2 = fmaf(v, __uint_as_float(y.y << 16), acc2);
            acc3 = fmaf(v, __uint_as_float(y.y & 0xFFFF0000u), acc3);
            acc4 = fmaf(v, __uint_as_float(y.z << 16), acc4);
            acc5 = fmaf(v, __uint_as_float(y.z & 0xFFFF0000u), acc5);
            acc6 = fmaf(v, __uint_as_float(y.w << 16), acc6);
            acc7 = fmaf(v, __uint_as_float(y.w & 0xFFFF0000u), acc7);
        }
        // reduce across the 4 sub-groups (lanes differing in bits 5 and 4)
        acc0 += __shfl_xor(acc0, 32); acc1 += __shfl_xor(acc1, 32);
        acc2 += __shfl_xor(acc2, 32); acc3 += __shfl_xor(acc3, 32);
        acc4 += __shfl_xor(acc4, 32); acc5 += __shfl_xor(acc5, 32);
        acc6 += __shfl_xor(acc6, 32); acc7 += __shfl_xor(acc7, 32);
        acc0 += __shfl_xor(acc0, 16); acc1 += __shfl_xor(acc1, 16);
        acc2 += __shfl_xor(acc2, 16); acc3 += __shfl_xor(acc3, 16);
        acc4 += __shfl_xor(acc4, 16); acc5 += __shfl_xor(acc5, 16);
        acc6 += __shfl_xor(acc6, 16); acc7 += __shfl_xor(acc7, 16);

        if (lane < 16) {
            float4 o0, o1;
            o0.x = acc0 > 0.f ? acc0 : __expf(acc0) - 1.f;
            o0.y = acc1 > 0.f ? acc1 : __expf(acc1) - 1.f;
            o0.z = acc2 > 0.f ? acc2 : __expf(acc2) - 1.f;
            o0.w = acc3 > 0.f ? acc3 : __expf(acc3) - 1.f;
            o1.x = acc4 > 0.f ? acc4 : __expf(acc4) - 1.f;
            o1.y = acc5 > 0.f ? acc5 : __expf(acc5) - 1.f;
            o1.z = acc6 > 0.f ? acc6 : __expf(acc6) - 1.f;
            o1.w = acc7 > 0.f ? acc7 : __expf(acc7) - 1.f;
            float* po = &out[(size_t)gr * 128 + qlane * 8];
            *(float4*)po       = o0;
            *(float4*)(po + 4) = o1;
        }
    }
}

// ---------------- Fallback path (fp32, atomic scatter) -----------------------
__global__ __launch_bounds__(256) void gemm_bias_kernel(
    const float* __restrict__ x, const float* __restrict__ W,
    const float* __restrict__ b, float* __restrict__ Y, int N)
{
    __shared__ float Wt[128][130];
    const int tid  = threadIdx.x;
    const int wave = tid >> 6;
    const int lane = tid & 63;
    for (int i = tid; i < 128 * 128; i += 256) {
        const int o = i >> 7, k = i & 127;
        Wt[k][o] = W[i];
    }
    __syncthreads();
    const float2 bv = *(const float2*)&b[2 * lane];
    for (int row = blockIdx.x * 4 + wave; row < N; row += gridDim.x * 4) {
        float acc0 = 0.f, acc1 = 0.f;
        for (int k = 0; k < 128; ++k) {
            const float2 w = *(const float2*)&Wt[k][2 * lane];
            const float xv = x[(size_t)row * 128 + k];
            acc0 = fmaf(xv, w.x, acc0);
            acc1 = fmaf(xv, w.y, acc1);
        }
        float2 o2; o2.x = acc0 + bv.x; o2.y = acc1 + bv.y;
        *(float2*)&Y[(size_t)row * 128 + 2 * lane] = o2;
    }
}

__global__ __launch_bounds__(256) void scatter_kernel(
    const int* __restrict__ rows, const int* __restrict__ cols,
    const float* __restrict__ vals, const float* __restrict__ Y,
    float* __restrict__ out, int E)
{
    const long long gid = (long long)blockIdx.x * blockDim.x + threadIdx.x;
    const int wid  = (int)(gid >> 6);
    const int lane = threadIdx.x & 63;
    if (wid >= E) return;
    const int   r = rows[wid];
    const int   c = cols[wid];
    const float v = vals[wid];
    const float2 y = *(const float2*)&Y[(size_t)c * 128 + 2 * lane];
    float* po = &out[(size_t)r * 128 + 2 * lane];
    atomicAdd(po,     v * y.x);
    atomicAdd(po + 1, v * y.y);
}

__global__ __launch_bounds__(256) void elu_kernel(float* __restrict__ out, int n4)
{
    int i = blockIdx.x * blockDim.x + threadIdx.x;
    const int stride = gridDim.x * blockDim.x;
    float4* p = (float4*)out;
    for (; i < n4; i += stride) {
        float4 v = p[i];
        v.x = v.x > 0.f ? v.x : expf(v.x) - 1.f;
        v.y = v.y > 0.f ? v.y : expf(v.y) - 1.f;
        v.z = v.z > 0.f ? v.z : expf(v.z) - 1.f;
        v.w = v.w > 0.f ? v.w : expf(v.w) - 1.f;
        p[i] = v;
    }
}

// -----------------------------------------------------------------------------
extern "C" void kernel_launch(void* const* d_in, const int* in_sizes, int n_in,
                              void* d_out, int out_size, void* d_ws, size_t ws_size,
                              hipStream_t stream)
{
    const float* x    = (const float*)d_in[0];
    const float* W    = (const float*)d_in[1];
    const float* b    = (const float*)d_in[2];
    const int*   rows = (const int*)d_in[3];
    const int*   cols = (const int*)d_in[4];
    const float* vals = (const float*)d_in[5];
    float* out = (float*)d_out;

    const int N   = in_sizes[0] / 128;
    const int E   = in_sizes[3];
    const int NB  = (N + RPB - 1) / RPB;               // fine buckets
    const int NSB = (N + (1 << SB_SHIFT) - 1) >> SB_SHIFT;  // super-buckets

    // SB_CAP = mean + ~10 sigma, 64-aligned
    const int sb_mean = (E + NSB - 1) / NSB;
    int sbsig = 1; while (sbsig * sbsig < sb_mean) ++sbsig;
    const int SB_CAP = (sb_mean + 10 * sbsig + 63) & ~63;

    auto align256 = [](size_t v) { return (v + 255) & ~(size_t)255; };
    // shared (aliased) layout — serialized fallback
    const size_t offPairs2 = 0;
    const size_t szPairs2  = (size_t)NB * FB_CAP * 8;
    const size_t offShared = align256(offPairs2 + szPairs2);   // pairs1 then Y
    const size_t szPairs1  = (size_t)NSB * SB_CAP * 8;
    const size_t szY       = (size_t)N * 256;
    const size_t szShared  = szPairs1 > szY ? szPairs1 : szY;
    const size_t offCur1_a = align256(offShared + szShared);
    const size_t offCur2_a = align256(offCur1_a + (size_t)NSB_MAX * 4 * CPAD);
    const size_t offWb_a   = align256(offCur2_a + (size_t)NB * 4);
    const size_t need      = offWb_a + 128 * 128 * 2;
    // un-aliased layout — overlap path
    const size_t offPairs1 = offShared;
    const size_t offY      = align256(offPairs1 + szPairs1);
    const size_t offCur1_o = align256(offY + szY);
    const size_t offCur2_o = align256(offCur1_o + (size_t)NSB_MAX * 4 * CPAD);
    const size_t offWb_o   = align256(offCur2_o + (size_t)NB * 4);
    const size_t need_ovl  = offWb_o + 128 * 128 * 2;

    const bool csr_ok = (need <= ws_size) && (NSB <= NSB_MAX) &&
                        ((long long)E <= (long long)NB * 1056) &&
                        (SB_CAP <= CH_PER_SB * TILE);
    const bool ovl_ok = csr_ok && (need_ovl <= ws_size);

    if (ovl_ok) {
        int2* pairs2        = (int2*)((char*)d_ws + offPairs2);
        int2* pairs1        = (int2*)((char*)d_ws + offPairs1);
        unsigned short* Yb  = (unsigned short*)((char*)d_ws + offY);
        int*  cursor1       = (int*)((char*)d_ws + offCur1_o);
        int*  cursor2       = (int*)((char*)d_ws + offCur2_o);
        unsigned short* Wbg = (unsigned short*)((char*)d_ws + offWb_o);

        const int GB = (N + 63) / 64;
        const int PB = (E + TILE - 1) / TILE;
        const int smsz = 128 * 136 * 2;    // 34816 B (gemm side; pass1 fits)
        const int NB1 = NB / 2;

        init_cursor_kernel<<<(NB + 255) / 256, 256, 0, stream>>>(cursor1, cursor2,
                                                                 SB_CAP, NB, W, Wbg);
        fused_gemm_pass1_kernel<<<GB + PB, 256, smsz, stream>>>(
            x, Wbg, b, Yb, N, GB, rows, cols, vals, cursor1, pairs1, E, PB);
        pass2_kernel<<<NSB * CH_PER_SB, 256, 0, stream>>>(cursor1, cursor2,
                                                          pairs1, pairs2, SB_CAP);
        sortgather_kernel<<<NB1, 256, 0, stream>>>(cursor2, pairs2,
                                                   (const unsigned int*)Yb, out, N, 0);
        sortgather_kernel<<<NB - NB1, 256, 0, stream>>>(cursor2, pairs2,
                                                        (const unsigned int*)Yb, out,
                                                        N, NB1);
    } else if (csr_ok) {
        int2* pairs2        = (int2*)((char*)d_ws + offPairs2);
        int2* pairs1        = (int2*)((char*)d_ws + offShared);
        unsigned short* Yb  = (unsigned short*)((char*)d_ws + offShared);
        int*  cursor1       = (int*)((char*)d_ws + offCur1_a);
        int*  cursor2       = (int*)((char*)d_ws + offCur2_a);
        unsigned short* Wbg = (unsigned short*)((char*)d_ws + offWb_a);

        init_cursor_kernel<<<(NB + 255) / 256, 256, 0, stream>>>(cursor1, cursor2,
                                                                 SB_CAP, NB, W, Wbg);
        pass1_kernel<<<(E + TILE - 1) / TILE, 256, 0, stream>>>(rows, cols, vals,
                                                                cursor1, pairs1, E);
        pass2_kernel<<<NSB * CH_PER_SB, 256, 0, stream>>>(cursor1, cursor2,
                                                          pairs1, pairs2, SB_CAP);
        // GEMM after pass2: Yb aliases pairs1 (dead now)
        gemm_mfma_kernel<<<(N + 63) / 64, 256, 0, stream>>>(x, Wbg, b, Yb, N);
        sortgather_kernel<<<NB, 256, 0, stream>>>(cursor2, pairs2,
                                                  (const unsigned int*)Yb, out, N, 0);
    } else {
        float* Y = (float*)d_ws;
        hipMemsetAsync(d_out, 0, (size_t)out_size * sizeof(float), stream);
        gemm_bias_kernel<<<512, 256, 0, stream>>>(x, W, b, Y, N);
        scatter_kernel<<<(E + 3) / 4, 256, 0, stream>>>(rows, cols, vals, Y, out, E);
        elu_kernel<<<1024, 256, 0, stream>>>(out, out_size / 4);
    }
}

// Round 13
// 282.240 us; speedup vs baseline: 1.0277x; 1.0277x over previous
//
#include <hip/hip_runtime.h>
#include <hip/hip_bf16.h>
#include <cmath>

#define RPB      32        // rows per fine bucket
#define FB_CAP   1280      // fine-bucket slot capacity (mean 1024, +8 sigma)
#define SB_SHIFT 11        // 2048 rows per super-bucket
#define NSB_MAX  64
#define TILE     2048      // edges per binning tile
#define CH_PER_SB 34       // pass-2 chunks per super-bucket (cap/34 <= TILE)
#define CPAD     32        // cursor1 padding: 1 counter per 128B line

typedef __attribute__((ext_vector_type(8))) short short8;
typedef __attribute__((ext_vector_type(4))) float floatx4;

__device__ __forceinline__ unsigned short f2bf(float f) {
    unsigned int u = __float_as_uint(f);
    u += 0x7FFFu + ((u >> 16) & 1u);   // RNE
    return (unsigned short)(u >> 16);
}

// ---------------- gemm body: A from x (reg), B staged in LDS -----------------
// (R11 version, verified.) Epilogue buffer reuses Wb: total LDS 34.8 KB.
__device__ __forceinline__ void gemm_body(
    char* smraw, const float* __restrict__ x,
    const unsigned short* __restrict__ Wbg, const float* __restrict__ b,
    unsigned short* __restrict__ Yb, int N, int blk)
{
    unsigned short* Wb = (unsigned short*)smraw;      // [128][136] = 34816 B
    const int t    = threadIdx.x;
    const int wave = t >> 6;
    const int lane = t & 63;
    const int col  = lane & 15;
    const int quad = lane >> 4;
    const int rowbase = blk * 64;
    const int mrow = wave * 16;

#pragma unroll
    for (int i = 0; i < 8; ++i) {          // W: 2048 chunks of 8 bf16 (16B)
        const int idx = t + 256 * i;
        const int o = idx >> 4, k8 = (idx & 15) * 8;
        *(uint4*)&Wb[o * 136 + k8] = *(const uint4*)&Wbg[idx * 8];
    }

    short8 af[4];
    const int arow = rowbase + mrow + col;
    if (arow < N) {
#pragma unroll
        for (int kk = 0; kk < 4; ++kk) {
            const float4 v0 = *(const float4*)&x[(size_t)arow * 128 + kk * 32 + quad * 8];
            const float4 v1 = *(const float4*)&x[(size_t)arow * 128 + kk * 32 + quad * 8 + 4];
            short8 a;
            a[0] = (short)f2bf(v0.x); a[1] = (short)f2bf(v0.y);
            a[2] = (short)f2bf(v0.z); a[3] = (short)f2bf(v0.w);
            a[4] = (short)f2bf(v1.x); a[5] = (short)f2bf(v1.y);
            a[6] = (short)f2bf(v1.z); a[7] = (short)f2bf(v1.w);
            af[kk] = a;
        }
    } else {
#pragma unroll
        for (int kk = 0; kk < 4; ++kk) {
            short8 a;
#pragma unroll
            for (int j = 0; j < 8; ++j) a[j] = 0;
            af[kk] = a;
        }
    }

    float bias[8];
#pragma unroll
    for (int nt = 0; nt < 8; ++nt) bias[nt] = b[nt * 16 + col];

    __syncthreads();                       // Wb staged

    floatx4 acc[8] = {};
#pragma unroll
    for (int kk = 0; kk < 4; ++kk) {
#pragma unroll
        for (int nt = 0; nt < 8; ++nt) {
            const short8 bf = *(const short8*)&Wb[(nt * 16 + col) * 136 + kk * 32 + quad * 8];
            acc[nt] = __builtin_amdgcn_mfma_f32_16x16x32_bf16(af[kk], bf, acc[nt], 0, 0, 0);
        }
    }
    __syncthreads();                       // all Wb reads done; reuse as Eb

    unsigned short* Eb = Wb;               // [64][136]
#pragma unroll
    for (int nt = 0; nt < 8; ++nt) {
#pragma unroll
        for (int reg = 0; reg < 4; ++reg)
            Eb[(mrow + quad * 4 + reg) * 136 + nt * 16 + col] =
                f2bf(acc[nt][reg] + bias[nt]);
    }
    __syncthreads();
#pragma unroll
    for (int i = 0; i < 4; ++i) {          // 1024 chunks of 16B: 64 rows x 16
        const int idx = t + 256 * i;
        const int row = idx >> 4, c16 = (idx & 15) * 8;
        const int gr  = rowbase + row;
        if (gr < N)
            *(uint4*)&Yb[(size_t)gr * 128 + c16] = *(const uint4*)&Eb[row * 136 + c16];
    }
}

// ---------------- pass1 body: register-held edges, direct sorted scatter -----
// (R12 version, kept: -5us net.) Edges live in registers across hist->scan;
// scatter writes DATA to sorted LDS slot (+1B bin tag); sequential stream out.
__device__ __forceinline__ void pass1_body(
    char* smraw, const int* __restrict__ rows, const int* __restrict__ cols,
    const float* __restrict__ vals, int* __restrict__ cursor1,
    int2* __restrict__ pairs1, int E, int blk)
{
    int2* sbuf            = (int2*)smraw;                      // [TILE] 16KB (sorted)
    unsigned char* sbin2  = (unsigned char*)(sbuf + TILE);     // [TILE] 2KB (bin@pos)
    int* hist  = (int*)(sbin2 + TILE);                         // [64]
    int* off   = hist + NSB_MAX;
    int* gbase = off + NSB_MAX;
    int* cur   = gbase + NSB_MAX;
    const int t  = threadIdx.x;
    const int lane = t & 63;
    const int lo = blk * TILE;
    const int cnt = min(TILE, E - lo);

    if (t < NSB_MAX) hist[t] = 0;
    __syncthreads();

    int2 pr[8];
    int  bn[8];
#pragma unroll
    for (int j = 0; j < 8; ++j) {          // TILE/256 == 8
        const int i = t + 256 * j;
        bn[j] = -1;
        if (i < cnt) {
            const int   r = rows[lo + i];
            const int   c = cols[lo + i];
            const float v = vals[lo + i];
            pr[j] = make_int2(((r & 2047) << 17) | c, __float_as_int(v));
            bn[j] = r >> SB_SHIFT;
            atomicAdd(&hist[bn[j]], 1);
        }
    }
    __syncthreads();
    if (t < NSB_MAX) {                     // wave-0 parallel exclusive scan
        const int h = hist[t];
        int s = h;
#pragma unroll
        for (int d = 1; d < NSB_MAX; d <<= 1) {
            const int n = __shfl_up(s, d);
            if (lane >= d) s += n;
        }
        off[t] = s - h;
        cur[t] = s - h;
        if (h > 0) gbase[t] = atomicAdd(&cursor1[t * CPAD], h);
    }
    __syncthreads();
#pragma unroll
    for (int j = 0; j < 8; ++j) {          // scatter data to sorted slot
        if (bn[j] >= 0) {
            const int pos = atomicAdd(&cur[bn[j]], 1);
            sbuf[pos]  = pr[j];
            sbin2[pos] = (unsigned char)bn[j];
        }
    }
    __syncthreads();
    for (int i = t; i < cnt; i += 256) {   // sequential stream to global runs
        const int bb = sbin2[i];
        pairs1[gbase[bb] + (i - off[bb])] = sbuf[i];
    }
}

// ---------------- K1: gemm ∥ pass1 (interleaved block types) -----------------
__global__ __launch_bounds__(256) void fused_gemm_pass1_kernel(
    const float* __restrict__ x, const unsigned short* __restrict__ Wbg,
    const float* __restrict__ b, unsigned short* __restrict__ Yb, int N, int GB,
    const int* __restrict__ rows, const int* __restrict__ cols,
    const float* __restrict__ vals, int* __restrict__ cursor1,
    int2* __restrict__ pairs1, int E, int PB)
{
    extern __shared__ __align__(16) char smraw[];
    const int bid = blockIdx.x;
    const int mn  = min(GB, PB);
    int type, sub;
    if (bid < 2 * mn) { type = bid & 1; sub = bid >> 1; }
    else              { type = (GB > PB) ? 0 : 1; sub = mn + (bid - 2 * mn); }
    if (type == 0) gemm_body(smraw, x, Wbg, b, Yb, N, sub);
    else           pass1_body(smraw, rows, cols, vals, cursor1, pairs1, E, sub);
}

// ---------------- standalone GEMM (fallback-serialized path) -----------------
__global__ __launch_bounds__(256) void gemm_mfma_kernel(
    const float* __restrict__ x, const unsigned short* __restrict__ Wbg,
    const float* __restrict__ b, unsigned short* __restrict__ Yb, int N)
{
    __shared__ __align__(16) char sm[128 * 136 * 2];
    gemm_body(sm, x, Wbg, b, Yb, N, blockIdx.x);
}

// ---------------- standalone pass1 (fallback-serialized path) ----------------
__global__ __launch_bounds__(256) void pass1_kernel(
    const int* __restrict__ rows, const int* __restrict__ cols,
    const float* __restrict__ vals, int* __restrict__ cursor1,
    int2* __restrict__ pairs1, int E)
{
    __shared__ __align__(16) char sm[TILE * 8 + TILE + NSB_MAX * 16];
    pass1_body(sm, rows, cols, vals, cursor1, pairs1, E, blockIdx.x);
}

// ---------------- P0: init cursors + convert W to bf16 -----------------------
__global__ __launch_bounds__(256) void init_cursor_kernel(
    int* __restrict__ cursor1, int* __restrict__ cursor2, int SB_CAP, int NB,
    const float* __restrict__ W, unsigned short* __restrict__ Wbg)
{
    const int i = blockIdx.x * blockDim.x + threadIdx.x;
    if (i < NSB_MAX) cursor1[i * CPAD] = i * SB_CAP;
    if (i < NB)      cursor2[i] = i * FB_CAP;
    const int stride = gridDim.x * blockDim.x;
    for (int j = i; j < 128 * 128 / 4; j += stride) {
        const float4 v = ((const float4*)W)[j];
        uint2 u;
        u.x = (unsigned)f2bf(v.x) | ((unsigned)f2bf(v.y) << 16);
        u.y = (unsigned)f2bf(v.z) | ((unsigned)f2bf(v.w) << 16);
        ((uint2*)Wbg)[j] = u;
    }
}

// ---------------- P2: register-held chunk sort by fine bucket ----------------
// (R12 version, kept.)
__global__ __launch_bounds__(256) void pass2_kernel(
    const int* __restrict__ cursor1, int* __restrict__ cursor2,
    const int2* __restrict__ pairs1, int2* __restrict__ pairs2, int SB_CAP)
{
    __shared__ __align__(16) int2 sbuf[TILE];
    __shared__ unsigned char sbin2[TILE];
    __shared__ int hist[64], off[64], gbase[64], cur[64];
    const int t   = threadIdx.x;
    const int lane = t & 63;
    const int sb  = blockIdx.x / CH_PER_SB;
    const int ch  = blockIdx.x % CH_PER_SB;
    const int base = sb * SB_CAP;
    const int scnt = cursor1[sb * CPAD] - base;
    const int csz  = (scnt + CH_PER_SB - 1) / CH_PER_SB;
    const int lo   = ch * csz;
    const int cnt  = max(0, min(csz, scnt - lo));

    if (t < 64) hist[t] = 0;
    __syncthreads();

    int2 pr[8];
    int  bn[8];
#pragma unroll
    for (int j = 0; j < 8; ++j) {          // csz <= TILE == 8*256
        const int i = t + 256 * j;
        bn[j] = -1;
        if (i < cnt) {
            const int2 p = pairs1[base + lo + i];
            pr[j] = p;
            bn[j] = (int)((unsigned)p.x >> 22);
            atomicAdd(&hist[bn[j]], 1);
        }
    }
    __syncthreads();
    if (t < 64) {                          // wave-0 parallel exclusive scan
        const int h = hist[t];
        int s = h;
#pragma unroll
        for (int d = 1; d < 64; d <<= 1) {
            const int n = __shfl_up(s, d);
            if (lane >= d) s += n;
        }
        off[t] = s - h;
        cur[t] = s - h;
        if (h > 0) gbase[t] = atomicAdd(&cursor2[sb * 64 + t], h);
    }
    __syncthreads();
#pragma unroll
    for (int j = 0; j < 8; ++j) {          // scatter data to sorted slot
        if (bn[j] >= 0) {
            const int pos = atomicAdd(&cur[bn[j]], 1);
            sbuf[pos]  = make_int2(pr[j].x & 0x3FFFFF, pr[j].y);  // keep ((row&31)<<17)|col
            sbin2[pos] = (unsigned char)bn[j];
        }
    }
    __syncthreads();
    for (int i = t; i < cnt; i += 256) {   // sequential stream to global runs
        const int bb = sbin2[i];
        pairs2[gbase[bb] + (i - off[bb])] = sbuf[i];
    }
}

// ---------------- P3: counting-sort + 4-edge-wide gather + ELU ---------------
// FROZEN at ~115us, UNSPLIT (R12 split cost +12us: half-grids are single
// residency waves with no backfill). R10 diet version.
__global__ __launch_bounds__(256) void sortgather_kernel(
    const int* __restrict__ cursor2, const int2* __restrict__ pairs2,
    const unsigned int* __restrict__ Yu, float* __restrict__ out, int N)
{
    __shared__ __align__(16) int2 dbuf[FB_CAP + 4];
    __shared__ int hist[RPB];
    __shared__ int off[RPB];
    __shared__ int cur[RPB];
    __shared__ int rowtick;
    const int b    = blockIdx.x;
    const int t    = threadIdx.x;
    const int lane = t & 63;
    const int slot = b * FB_CAP;
    int cnt = cursor2[b] - slot;
    if (cnt > FB_CAP) cnt = FB_CAP;

    if (t < RPB) hist[t] = 0;
    if (t == 0) rowtick = 0;
    __syncthreads();
    for (int i = t; i < cnt; i += 256) {       // pass A: histogram (global read)
        atomicAdd(&hist[pairs2[slot + i].x >> 17], 1);
    }
    __syncthreads();
    if (t == 0) {
        int run = 0;
#pragma unroll
        for (int k = 0; k < RPB; ++k) { off[k] = run; cur[k] = run; run += hist[k]; }
    }
    __syncthreads();
    for (int i = t; i < cnt; i += 256) {       // pass B: scatter (global re-read)
        const int2 p   = pairs2[slot + i];
        const int  pos = atomicAdd(&cur[p.x >> 17], 1);
        dbuf[pos] = make_int2(p.x & 0x1FFFF, p.y);
    }
    if (t < 4) dbuf[cnt + t] = make_int2(0, 0);   // pad: tail over-reads hit row 0, v=0
    __syncthreads();

    const int sub   = lane >> 4;   // which of the 4 edges in a chunk
    const int qlane = lane & 15;   // 16 lanes span one 256B Y row (dwordx4 each)

    for (;;) {
        int rl = 0;
        if (lane == 0) rl = atomicAdd(&rowtick, 1);
        rl = __shfl(rl, 0);
        if (rl >= RPB) break;
        const int gr = b * RPB + rl;
        if (gr >= N) continue;
        const int s = off[rl];
        const int e = s + hist[rl];

        float acc0 = 0.f, acc1 = 0.f, acc2 = 0.f, acc3 = 0.f;
        float acc4 = 0.f, acc5 = 0.f, acc6 = 0.f, acc7 = 0.f;
#pragma unroll 2
        for (int j = s; j < e; j += 4) {
            const int2 p = dbuf[j + sub];            // 4 distinct broadcast addrs
            float v = __int_as_float(p.y);
            v = (j + sub < e) ? v : 0.0f;            // mask tail (y stays valid)
            const uint4 y = *(const uint4*)&Yu[((unsigned)p.x << 6) + qlane * 4];
            acc0 = fmaf(v, __uint_as_float(y.x << 16), acc0);
            acc1 = fmaf(v, __uint_as_float(y.x & 0xFFFF0000u), acc1);
            acc2 = fmaf(v, __uint_as_float(y.y << 16), acc2);
            acc3 = fmaf(v, __uint_as_float(y.y & 0xFFFF0000u), acc3);
            acc4 = fmaf(v, __uint_as_float(y.z << 16), acc4);
            acc5 = fmaf(v, __uint_as_float(y.z & 0xFFFF0000u), acc5);
            acc6 = fmaf(v, __uint_as_float(y.w << 16), acc6);
            acc7 = fmaf(v, __uint_as_float(y.w & 0xFFFF0000u), acc7);
        }
        // reduce across the 4 sub-groups (lanes differing in bits 5 and 4)
        acc0 += __shfl_xor(acc0, 32); acc1 += __shfl_xor(acc1, 32);
        acc2 += __shfl_xor(acc2, 32); acc3 += __shfl_xor(acc3, 32);
        acc4 += __shfl_xor(acc4, 32); acc5 += __shfl_xor(acc5, 32);
        acc6 += __shfl_xor(acc6, 32); acc7 += __shfl_xor(acc7, 32);
        acc0 += __shfl_xor(acc0, 16); acc1 += __shfl_xor(acc1, 16);
        acc2 += __shfl_xor(acc2, 16); acc3 += __shfl_xor(acc3, 16);
        acc4 += __shfl_xor(acc4, 16); acc5 += __shfl_xor(acc5, 16);
        acc6 += __shfl_xor(acc6, 16); acc7 += __shfl_xor(acc7, 16);

        if (lane < 16) {
            float4 o0, o1;
            o0.x = acc0 > 0.f ? acc0 : __expf(acc0) - 1.f;
            o0.y = acc1 > 0.f ? acc1 : __expf(acc1) - 1.f;
            o0.z = acc2 > 0.f ? acc2 : __expf(acc2) - 1.f;
            o0.w = acc3 > 0.f ? acc3 : __expf(acc3) - 1.f;
            o1.x = acc4 > 0.f ? acc4 : __expf(acc4) - 1.f;
            o1.y = acc5 > 0.f ? acc5 : __expf(acc5) - 1.f;
            o1.z = acc6 > 0.f ? acc6 : __expf(acc6) - 1.f;
            o1.w = acc7 > 0.f ? acc7 : __expf(acc7) - 1.f;
            float* po = &out[(size_t)gr * 128 + qlane * 8];
            *(float4*)po       = o0;
            *(float4*)(po + 4) = o1;
        }
    }
}

// ---------------- Fallback path (fp32, atomic scatter) -----------------------
__global__ __launch_bounds__(256) void gemm_bias_kernel(
    const float* __restrict__ x, const float* __restrict__ W,
    const float* __restrict__ b, float* __restrict__ Y, int N)
{
    __shared__ float Wt[128][130];
    const int tid  = threadIdx.x;
    const int wave = tid >> 6;
    const int lane = tid & 63;
    for (int i = tid; i < 128 * 128; i += 256) {
        const int o = i >> 7, k = i & 127;
        Wt[k][o] = W[i];
    }
    __syncthreads();
    const float2 bv = *(const float2*)&b[2 * lane];
    for (int row = blockIdx.x * 4 + wave; row < N; row += gridDim.x * 4) {
        float acc0 = 0.f, acc1 = 0.f;
        for (int k = 0; k < 128; ++k) {
            const float2 w = *(const float2*)&Wt[k][2 * lane];
            const float xv = x[(size_t)row * 128 + k];
            acc0 = fmaf(xv, w.x, acc0);
            acc1 = fmaf(xv, w.y, acc1);
        }
        float2 o2; o2.x = acc0 + bv.x; o2.y = acc1 + bv.y;
        *(float2*)&Y[(size_t)row * 128 + 2 * lane] = o2;
    }
}

__global__ __launch_bounds__(256) void scatter_kernel(
    const int* __restrict__ rows, const int* __restrict__ cols,
    const float* __restrict__ vals, const float* __restrict__ Y,
    float* __restrict__ out, int E)
{
    const long long gid = (long long)blockIdx.x * blockDim.x + threadIdx.x;
    const int wid  = (int)(gid >> 6);
    const int lane = threadIdx.x & 63;
    if (wid >= E) return;
    const int   r = rows[wid];
    const int   c = cols[wid];
    const float v = vals[wid];
    const float2 y = *(const float2*)&Y[(size_t)c * 128 + 2 * lane];
    float* po = &out[(size_t)r * 128 + 2 * lane];
    atomicAdd(po,     v * y.x);
    atomicAdd(po + 1, v * y.y);
}

__global__ __launch_bounds__(256) void elu_kernel(float* __restrict__ out, int n4)
{
    int i = blockIdx.x * blockDim.x + threadIdx.x;
    const int stride = gridDim.x * blockDim.x;
    float4* p = (float4*)out;
    for (; i < n4; i += stride) {
        float4 v = p[i];
        v.x = v.x > 0.f ? v.x : expf(v.x) - 1.f;
        v.y = v.y > 0.f ? v.y : expf(v.y) - 1.f;
        v.z = v.z > 0.f ? v.z : expf(v.z) - 1.f;
        v.w = v.w > 0.f ? v.w : expf(v.w) - 1.f;
        p[i] = v;
    }
}

// -----------------------------------------------------------------------------
extern "C" void kernel_launch(void* const* d_in, const int* in_sizes, int n_in,
                              void* d_out, int out_size, void* d_ws, size_t ws_size,
                              hipStream_t stream)
{
    const float* x    = (const float*)d_in[0];
    const float* W    = (const float*)d_in[1];
    const float* b    = (const float*)d_in[2];
    const int*   rows = (const int*)d_in[3];
    const int*   cols = (const int*)d_in[4];
    const float* vals = (const float*)d_in[5];
    float* out = (float*)d_out;

    const int N   = in_sizes[0] / 128;
    const int E   = in_sizes[3];
    const int NB  = (N + RPB - 1) / RPB;               // fine buckets
    const int NSB = (N + (1 << SB_SHIFT) - 1) >> SB_SHIFT;  // super-buckets

    // SB_CAP = mean + ~10 sigma, 64-aligned
    const int sb_mean = (E + NSB - 1) / NSB;
    int sbsig = 1; while (sbsig * sbsig < sb_mean) ++sbsig;
    const int SB_CAP = (sb_mean + 10 * sbsig + 63) & ~63;

    auto align256 = [](size_t v) { return (v + 255) & ~(size_t)255; };
    // shared (aliased) layout — serialized fallback
    const size_t offPairs2 = 0;
    const size_t szPairs2  = (size_t)NB * FB_CAP * 8;
    const size_t offShared = align256(offPairs2 + szPairs2);   // pairs1 then Y
    const size_t szPairs1  = (size_t)NSB * SB_CAP * 8;
    const size_t szY       = (size_t)N * 256;
    const size_t szShared  = szPairs1 > szY ? szPairs1 : szY;
    const size_t offCur1_a = align256(offShared + szShared);
    const size_t offCur2_a = align256(offCur1_a + (size_t)NSB_MAX * 4 * CPAD);
    const size_t offWb_a   = align256(offCur2_a + (size_t)NB * 4);
    const size_t need      = offWb_a + 128 * 128 * 2;
    // un-aliased layout — overlap path
    const size_t offPairs1 = offShared;
    const size_t offY      = align256(offPairs1 + szPairs1);
    const size_t offCur1_o = align256(offY + szY);
    const size_t offCur2_o = align256(offCur1_o + (size_t)NSB_MAX * 4 * CPAD);
    const size_t offWb_o   = align256(offCur2_o + (size_t)NB * 4);
    const size_t need_ovl  = offWb_o + 128 * 128 * 2;

    const bool csr_ok = (need <= ws_size) && (NSB <= NSB_MAX) &&
                        ((long long)E <= (long long)NB * 1056) &&
                        (SB_CAP <= CH_PER_SB * TILE);
    const bool ovl_ok = csr_ok && (need_ovl <= ws_size);

    if (ovl_ok) {
        int2* pairs2        = (int2*)((char*)d_ws + offPairs2);
        int2* pairs1        = (int2*)((char*)d_ws + offPairs1);
        unsigned short* Yb  = (unsigned short*)((char*)d_ws + offY);
        int*  cursor1       = (int*)((char*)d_ws + offCur1_o);
        int*  cursor2       = (int*)((char*)d_ws + offCur2_o);
        unsigned short* Wbg = (unsigned short*)((char*)d_ws + offWb_o);

        const int GB = (N + 63) / 64;
        const int PB = (E + TILE - 1) / TILE;
        const int smsz = 128 * 136 * 2;    // 34816 B (gemm side; pass1 fits)

        init_cursor_kernel<<<(NB + 255) / 256, 256, 0, stream>>>(cursor1, cursor2,
                                                                 SB_CAP, NB, W, Wbg);
        fused_gemm_pass1_kernel<<<GB + PB, 256, smsz, stream>>>(
            x, Wbg, b, Yb, N, GB, rows, cols, vals, cursor1, pairs1, E, PB);
        pass2_kernel<<<NSB * CH_PER_SB, 256, 0, stream>>>(cursor1, cursor2,
                                                          pairs1, pairs2, SB_CAP);
        sortgather_kernel<<<NB, 256, 0, stream>>>(cursor2, pairs2,
                                                  (const unsigned int*)Yb, out, N);
    } else if (csr_ok) {
        int2* pairs2        = (int2*)((char*)d_ws + offPairs2);
        int2* pairs1        = (int2*)((char*)d_ws + offShared);
        unsigned short* Yb  = (unsigned short*)((char*)d_ws + offShared);
        int*  cursor1       = (int*)((char*)d_ws + offCur1_a);
        int*  cursor2       = (int*)((char*)d_ws + offCur2_a);
        unsigned short* Wbg = (unsigned short*)((char*)d_ws + offWb_a);

        init_cursor_kernel<<<(NB + 255) / 256, 256, 0, stream>>>(cursor1, cursor2,
                                                                 SB_CAP, NB, W, Wbg);
        pass1_kernel<<<(E + TILE - 1) / TILE, 256, 0, stream>>>(rows, cols, vals,
                                                                cursor1, pairs1, E);
        pass2_kernel<<<NSB * CH_PER_SB, 256, 0, stream>>>(cursor1, cursor2,
                                                          pairs1, pairs2, SB_CAP);
        // GEMM after pass2: Yb aliases pairs1 (dead now)
        gemm_mfma_kernel<<<(N + 63) / 64, 256, 0, stream>>>(x, Wbg, b, Yb, N);
        sortgather_kernel<<<NB, 256, 0, stream>>>(cursor2, pairs2,
                                                  (const unsigned int*)Yb, out, N);
    } else {
        float* Y = (float*)d_ws;
        hipMemsetAsync(d_out, 0, (size_t)out_size * sizeof(float), stream);
        gemm_bias_kernel<<<512, 256, 0, stream>>>(x, W, b, Y, N);
        scatter_kernel<<<(E + 3) / 4, 256, 0, stream>>>(rows, cols, vals, Y, out, E);
        elu_kernel<<<1024, 256, 0, stream>>>(out, out_size / 4);
    }
}